// Round 8
// baseline (165.050 us; speedup 1.0000x reference)
//
#include <hip/hip_runtime.h>

#define T_SEQ 2048
#define NH 4
#define DH 64

typedef __bf16 bf16x8 __attribute__((ext_vector_type(8)));
typedef float f32x4 __attribute__((ext_vector_type(4)));
typedef unsigned short u16x8 __attribute__((ext_vector_type(8)));

__device__ __forceinline__ unsigned short f2bf_rne(float x) {
  unsigned int u = __builtin_bit_cast(unsigned int, x);
  u += 0x7fffu + ((u >> 16) & 1u);
  return (unsigned short)(u >> 16);
}

__device__ __forceinline__ void async_cp16(const unsigned short* g, unsigned short* l) {
  __builtin_amdgcn_global_load_lds(
      (const __attribute__((address_space(1))) unsigned int*)g,
      (__attribute__((address_space(3))) unsigned int*)l, 16, 0, 0);
}

// ---------------------------------------------------------------------------
// wprep: W (256x256 fp32, [k][n]) -> Wt ([n][k] bf16, hi plane + lo plane).
// ---------------------------------------------------------------------------
__global__ __launch_bounds__(256) void wprep(const float* __restrict__ W,
                                             unsigned short* __restrict__ Wt) {
  int tid = blockIdx.x * 256 + threadIdx.x;  // 65536 elems
  int k = tid >> 8, n = tid & 255;
  float w = W[tid];
  unsigned int u = __builtin_bit_cast(unsigned int, w);
  Wt[n * 256 + k] = (unsigned short)(u >> 16);
  float lo = w - __builtin_bit_cast(float, u & 0xffff0000u);
  Wt[65536 + n * 256 + k] =
      (unsigned short)(__builtin_bit_cast(unsigned int, lo) >> 16);
}

// ---------------------------------------------------------------------------
// wh_gemm v3 (identical to round-3): bf16 MFMA hi/lo split GEMM.
// ---------------------------------------------------------------------------
__global__ __launch_bounds__(256, 2) void wh_gemm(
    const float* __restrict__ h, const unsigned short* __restrict__ Wt,
    unsigned short* __restrict__ Kb, unsigned short* __restrict__ Vt) {
  __shared__ __align__(16) unsigned short Ahi[32 * 256];  // [row][chunk^row&7]
  __shared__ __align__(16) unsigned short Alo[32 * 256];
  const int tid = threadIdx.x;
  const int wave = tid >> 6;
  const int lane = tid & 63;
  const int l15 = lane & 15;
  const int quad = lane >> 4;
  const int mbase = blockIdx.x * 32;  // 512 blocks
  const int col0 = wave * 64;         // one head per wave

  {
    const int r = tid >> 3;
    const int cbase = (tid & 7) * 4;
    const float4* hp = (const float4*)(h + ((size_t)(mbase + r) << 8) + cbase * 8);
#pragma unroll
    for (int j = 0; j < 4; j++) {
      float4 f0 = hp[2 * j];
      float4 f1 = hp[2 * j + 1];
      u16x8 hi, lo;
#define SPLIT1(v, idx)                                                    \
  {                                                                       \
    unsigned int u_ = __builtin_bit_cast(unsigned int, (v));              \
    hi[idx] = (unsigned short)(u_ >> 16);                                 \
    float r_ = (v) - __builtin_bit_cast(float, u_ & 0xffff0000u);         \
    lo[idx] = (unsigned short)(__builtin_bit_cast(unsigned int, r_) >> 16); \
  }
      SPLIT1(f0.x, 0) SPLIT1(f0.y, 1) SPLIT1(f0.z, 2) SPLIT1(f0.w, 3)
      SPLIT1(f1.x, 4) SPLIT1(f1.y, 5) SPLIT1(f1.z, 6) SPLIT1(f1.w, 7)
#undef SPLIT1
      const int chunk = (cbase + j) ^ (r & 7);
      *(u16x8*)&Ahi[r * 256 + chunk * 8] = hi;
      *(u16x8*)&Alo[r * 256 + chunk * 8] = lo;
    }
  }
  __syncthreads();

  f32x4 acc[2][4];
#pragma unroll
  for (int mt = 0; mt < 2; mt++)
#pragma unroll
    for (int nt = 0; nt < 4; nt++) acc[mt][nt] = (f32x4){0.f, 0.f, 0.f, 0.f};

#pragma unroll 2
  for (int ks = 0; ks < 8; ks++) {
    const int k0 = ks * 32 + quad * 8;
    bf16x8 ahi[2], alo[2];
#pragma unroll
    for (int mt = 0; mt < 2; mt++) {
      const int row = mt * 16 + l15;
      const int ch = (ks * 4 + quad) ^ (row & 7);
      ahi[mt] = *(const bf16x8*)&Ahi[row * 256 + ch * 8];
      alo[mt] = *(const bf16x8*)&Alo[row * 256 + ch * 8];
    }
#pragma unroll
    for (int nt = 0; nt < 4; nt++) {
      const unsigned short* wp = Wt + ((size_t)(col0 + nt * 16 + l15) << 8) + k0;
      bf16x8 bhi = *(const bf16x8*)wp;
      bf16x8 blo = *(const bf16x8*)(wp + 65536);
#pragma unroll
      for (int mt = 0; mt < 2; mt++) {
        acc[mt][nt] = __builtin_amdgcn_mfma_f32_16x16x32_bf16(ahi[mt], bhi, acc[mt][nt], 0, 0, 0);
        acc[mt][nt] = __builtin_amdgcn_mfma_f32_16x16x32_bf16(alo[mt], bhi, acc[mt][nt], 0, 0, 0);
        acc[mt][nt] = __builtin_amdgcn_mfma_f32_16x16x32_bf16(ahi[mt], blo, acc[mt][nt], 0, 0, 0);
      }
    }
  }

  const float s1 = 0.424664717f;  // sqrt(log2(e)/8)
#pragma unroll
  for (int mt = 0; mt < 2; mt++) {
    int row = mbase + mt * 16 + quad * 4;
    int b = row >> 11;
    int tb = row & 2047;
    size_t bh = (size_t)(b * NH + wave);
#pragma unroll
    for (int nt = 0; nt < 4; nt++) {
      int d = nt * 16 + l15;
      Kb[(bh * T_SEQ + tb + 0) * DH + d] = f2bf_rne(acc[mt][nt][0] * s1);
      Kb[(bh * T_SEQ + tb + 1) * DH + d] = f2bf_rne(acc[mt][nt][1] * s1);
      Kb[(bh * T_SEQ + tb + 2) * DH + d] = f2bf_rne(acc[mt][nt][2] * s1);
      Kb[(bh * T_SEQ + tb + 3) * DH + d] = f2bf_rne(acc[mt][nt][3] * s1);
      ushort4 vp;
      vp.x = f2bf_rne(acc[mt][nt][0]);
      vp.y = f2bf_rne(acc[mt][nt][1]);
      vp.z = f2bf_rne(acc[mt][nt][2]);
      vp.w = f2bf_rne(acc[mt][nt][3]);
      *(ushort4*)&Vt[(bh * DH + d) * T_SEQ + tb] = vp;
    }
  }
}

// ---------------------------------------------------------------------------
// attn: round-3 code, split into two 512-block dispatches via gbase so the
// ~70us monolith becomes two ~35-45us halves -> wh_gemm surfaces in top-5
// rocprof rows with full counters (this round is the visibility experiment).
// Blocks are independent; split is trivially correct.
// ---------------------------------------------------------------------------
__global__ __launch_bounds__(256, 4) void attn(
    const unsigned short* __restrict__ Kb, const unsigned short* __restrict__ Vt,
    float* __restrict__ out, int gbase) {
  __shared__ __align__(16) unsigned short ldsK[2][64 * 64];
  __shared__ __align__(16) unsigned short ldsV[2][64 * 64];
  __shared__ __align__(16) unsigned short ldsP[4][16 * 64];
  const int tid = threadIdx.x;
  const int wave = tid >> 6;
  const int lane = tid & 63;
  const int l15 = lane & 15;
  const int quad = lane >> 4;
  const int g = gbase + blockIdx.x;  // logical id in [0,1024)
  const int lbid = (g & 7) * 128 + (g >> 3);  // XCD swizzle (same map as r3)
  const int bh = lbid >> 5;
  const int qtile = lbid & 31;
  const unsigned short* Kbh = Kb + (size_t)bh * T_SEQ * DH;
  const unsigned short* Vbh = Vt + (size_t)bh * DH * T_SEQ;

  const int qrow = qtile * 64 + wave * 16 + l15;
  bf16x8 aq0 = *(const bf16x8*)&Kbh[qrow * DH + quad * 8];
  bf16x8 aq1 = *(const bf16x8*)&Kbh[qrow * DH + 32 + quad * 8];

  f32x4 o[4];
  float lsum[4];
#pragma unroll
  for (int i = 0; i < 4; i++) {
    o[i] = (f32x4){0.f, 0.f, 0.f, 0.f};
    lsum[i] = 0.f;
  }
  unsigned short* Pw = ldsP[wave];

  auto stage = [&](int t, int buf) {
#pragma unroll
    for (int i = 0; i < 2; i++) {
      int slot = i * 256 + tid;
      int r = slot >> 3;
      int c = (slot & 7) ^ (r & 7);
      async_cp16(&Kbh[(t * 64 + r) * DH + c * 8],
                 &ldsK[buf][(i * 256 + wave * 64) * 8]);
      async_cp16(&Vbh[(size_t)r * T_SEQ + t * 64 + c * 8],
                 &ldsV[buf][(i * 256 + wave * 64) * 8]);
    }
  };

  stage(0, 0);

  for (int kt = 0; kt < 32; kt++) {
    const int cur = kt & 1;
    if (kt < 31) {
      stage(kt + 1, cur ^ 1);
      asm volatile("s_waitcnt vmcnt(4)" ::: "memory");
    } else {
      asm volatile("s_waitcnt vmcnt(0)" ::: "memory");
    }
    __builtin_amdgcn_s_barrier();
    __builtin_amdgcn_sched_barrier(0);

    const unsigned short* Kl = ldsK[cur];
    const unsigned short* Vl = ldsV[cur];

    f32x4 sfr[4];
    __builtin_amdgcn_s_setprio(1);
#pragma unroll
    for (int nt = 0; nt < 4; nt++) {
      int key = nt * 16 + l15;
      bf16x8 kf0 = *(const bf16x8*)&Kl[key * 64 + ((quad ^ (key & 7)) << 3)];
      bf16x8 kf1 = *(const bf16x8*)&Kl[key * 64 + (((4 + quad) ^ (key & 7)) << 3)];
      f32x4 s = {0.f, 0.f, 0.f, 0.f};
      s = __builtin_amdgcn_mfma_f32_16x16x32_bf16(aq0, kf0, s, 0, 0, 0);
      s = __builtin_amdgcn_mfma_f32_16x16x32_bf16(aq1, kf1, s, 0, 0, 0);
      sfr[nt] = s;
    }
    __builtin_amdgcn_s_setprio(0);

#pragma unroll
    for (int nt = 0; nt < 4; nt++) {
      int col = nt * 16 + l15;
#pragma unroll
      for (int reg = 0; reg < 4; reg++) {
        float v = sfr[nt][reg];
        float e = __builtin_amdgcn_exp2f(fmaxf(v, 0.2f * v));
        lsum[reg] += e;
        int row = quad * 4 + reg;
        Pw[(row << 6) + (((((col >> 3) ^ (row & 7))) << 3) | (col & 7))] =
            (unsigned short)(__builtin_bit_cast(unsigned int, e) >> 16);
      }
    }
    __builtin_amdgcn_s_waitcnt(0xC07F);  // lgkmcnt(0)

    __builtin_amdgcn_s_setprio(1);
#pragma unroll
    for (int kc = 0; kc < 2; kc++) {
      bf16x8 ap = *(const bf16x8*)&Pw[(l15 << 6) + ((((kc << 2) + quad) ^ (l15 & 7)) << 3)];
#pragma unroll
      for (int nt = 0; nt < 4; nt++) {
        int d = nt * 16 + l15;
        bf16x8 vf = *(const bf16x8*)&Vl[(d << 6) + ((((kc << 2) + quad) ^ (d & 7)) << 3)];
        o[nt] = __builtin_amdgcn_mfma_f32_16x16x32_bf16(ap, vf, o[nt], 0, 0, 0);
      }
    }
    __builtin_amdgcn_s_setprio(0);
    __builtin_amdgcn_sched_barrier(0);
    __builtin_amdgcn_s_barrier();
  }

  float inv[4];
#pragma unroll
  for (int reg = 0; reg < 4; reg++) {
    float l = lsum[reg];
    l += __shfl_xor(l, 1, 64);
    l += __shfl_xor(l, 2, 64);
    l += __shfl_xor(l, 4, 64);
    l += __shfl_xor(l, 8, 64);
    inv[reg] = 1.0f / l;
  }
  const int b = bh >> 2, head = bh & 3;
#pragma unroll
  for (int nt = 0; nt < 4; nt++) {
    int d = nt * 16 + l15;
#pragma unroll
    for (int reg = 0; reg < 4; reg++) {
      int trow = qtile * 64 + wave * 16 + quad * 4 + reg;
      out[((size_t)b * T_SEQ + trow) * 256 + head * 64 + d] = o[nt][reg] * inv[reg];
    }
  }
}

extern "C" void kernel_launch(void* const* d_in, const int* in_sizes, int n_in,
                              void* d_out, int out_size, void* d_ws, size_t ws_size,
                              hipStream_t stream) {
  const float* h = (const float*)d_in[0];
  const float* W = (const float*)d_in[1];
  float* out = (float*)d_out;
  // workspace: Kb 8 MB + Vt 8 MB + Wt 256 KB
  unsigned short* Kb = (unsigned short*)d_ws;
  unsigned short* Vt = Kb + (size_t)32 * T_SEQ * DH;
  unsigned short* Wt = Vt + (size_t)32 * T_SEQ * DH;
  wprep<<<256, 256, 0, stream>>>(W, Wt);
  wh_gemm<<<512, 256, 0, stream>>>(h, Wt, Kb, Vt);
  attn<<<512, 256, 0, stream>>>(Kb, Vt, out, 0);
  attn<<<512, 256, 0, stream>>>(Kb, Vt, out, 512);
}

// Round 9
// 158.771 us; speedup vs baseline: 1.0395x; 1.0395x over previous
//
#include <hip/hip_runtime.h>

#define T_SEQ 2048
#define NH 4
#define DH 64

typedef __bf16 bf16x8 __attribute__((ext_vector_type(8)));
typedef float f32x4 __attribute__((ext_vector_type(4)));
typedef unsigned short u16x8 __attribute__((ext_vector_type(8)));

__device__ __forceinline__ unsigned short f2bf_rne(float x) {
  unsigned int u = __builtin_bit_cast(unsigned int, x);
  u += 0x7fffu + ((u >> 16) & 1u);
  return (unsigned short)(u >> 16);
}

__device__ __forceinline__ void async_cp16(const unsigned short* g, unsigned short* l) {
  __builtin_amdgcn_global_load_lds(
      (const __attribute__((address_space(1))) unsigned int*)g,
      (__attribute__((address_space(3))) unsigned int*)l, 16, 0, 0);
}

// ---------------------------------------------------------------------------
// wprep: W (256x256 fp32, [k][n]) -> Wt ([n][k] bf16, hi plane + lo plane).
// ---------------------------------------------------------------------------
__global__ __launch_bounds__(256) void wprep(const float* __restrict__ W,
                                             unsigned short* __restrict__ Wt) {
  int tid = blockIdx.x * 256 + threadIdx.x;  // 65536 elems
  int k = tid >> 8, n = tid & 255;
  float w = W[tid];
  unsigned int u = __builtin_bit_cast(unsigned int, w);
  Wt[n * 256 + k] = (unsigned short)(u >> 16);
  float lo = w - __builtin_bit_cast(float, u & 0xffff0000u);
  Wt[65536 + n * 256 + k] =
      (unsigned short)(__builtin_bit_cast(unsigned int, lo) >> 16);
}

// ---------------------------------------------------------------------------
// wh_gemm v4: bf16 MFMA hi/lo split (D = AhBh + AhBl + AlBh).
// vs v3: (1) 1024 blocks x 16 rows, launch_bounds(256,4) -> 16 waves/CU
// (was 8) for latency hiding; (2) Vt written via per-wave LDS [d][t] staging
// (ds_write_b64 from t-major regs, linear ds_read_b128 back, 16B stores in
// 32B segments) instead of 8B x 4KB-stride scatter; (3) Kb scalar stores
// halved (16/thread).
// ---------------------------------------------------------------------------
__global__ __launch_bounds__(256, 4) void wh_gemm(
    const float* __restrict__ h, const unsigned short* __restrict__ Wt,
    unsigned short* __restrict__ Kb, unsigned short* __restrict__ Vt) {
  __shared__ __align__(16) unsigned short Ahi[16 * 256];  // [row][chunk^row&7]
  __shared__ __align__(16) unsigned short Alo[16 * 256];
  __shared__ __align__(16) unsigned short ldsT[4][64 * 16];  // per-wave [d][t]
  const int tid = threadIdx.x;
  const int wave = tid >> 6;
  const int lane = tid & 63;
  const int l15 = lane & 15;
  const int quad = lane >> 4;
  const int mbase = blockIdx.x * 16;  // 1024 blocks
  const int col0 = wave * 64;         // one head per wave

  {  // stage h tile: thread -> row tid>>4, 16 floats at col (tid&15)*16
    const int r = tid >> 4;
    const int c16 = tid & 15;
    const float4* hp = (const float4*)(h + ((size_t)(mbase + r) << 8)) + c16 * 4;
    float4 f0 = hp[0], f1 = hp[1], f2 = hp[2], f3 = hp[3];
    u16x8 hi0, lo0, hi1, lo1;
#define SPLIT1(dsthi, dstlo, idx, v)                                         \
  {                                                                          \
    unsigned int u_ = __builtin_bit_cast(unsigned int, (v));                 \
    dsthi[idx] = (unsigned short)(u_ >> 16);                                 \
    float r_ = (v) - __builtin_bit_cast(float, u_ & 0xffff0000u);            \
    dstlo[idx] = (unsigned short)(__builtin_bit_cast(unsigned int, r_) >> 16); \
  }
    SPLIT1(hi0, lo0, 0, f0.x) SPLIT1(hi0, lo0, 1, f0.y)
    SPLIT1(hi0, lo0, 2, f0.z) SPLIT1(hi0, lo0, 3, f0.w)
    SPLIT1(hi0, lo0, 4, f1.x) SPLIT1(hi0, lo0, 5, f1.y)
    SPLIT1(hi0, lo0, 6, f1.z) SPLIT1(hi0, lo0, 7, f1.w)
    SPLIT1(hi1, lo1, 0, f2.x) SPLIT1(hi1, lo1, 1, f2.y)
    SPLIT1(hi1, lo1, 2, f2.z) SPLIT1(hi1, lo1, 3, f2.w)
    SPLIT1(hi1, lo1, 4, f3.x) SPLIT1(hi1, lo1, 5, f3.y)
    SPLIT1(hi1, lo1, 6, f3.z) SPLIT1(hi1, lo1, 7, f3.w)
#undef SPLIT1
    const int ch0 = (c16 * 2) ^ (r & 7);
    const int ch1 = (c16 * 2 + 1) ^ (r & 7);
    *(u16x8*)&Ahi[r * 256 + ch0 * 8] = hi0;
    *(u16x8*)&Alo[r * 256 + ch0 * 8] = lo0;
    *(u16x8*)&Ahi[r * 256 + ch1 * 8] = hi1;
    *(u16x8*)&Alo[r * 256 + ch1 * 8] = lo1;
  }
  __syncthreads();

  f32x4 acc[4];
#pragma unroll
  for (int nt = 0; nt < 4; nt++) acc[nt] = (f32x4){0.f, 0.f, 0.f, 0.f};

#pragma unroll 2
  for (int ks = 0; ks < 8; ks++) {
    const int k0 = ks * 32 + quad * 8;
    const int ch = (ks * 4 + quad) ^ (l15 & 7);
    bf16x8 ahi = *(const bf16x8*)&Ahi[l15 * 256 + ch * 8];
    bf16x8 alo = *(const bf16x8*)&Alo[l15 * 256 + ch * 8];
#pragma unroll
    for (int nt = 0; nt < 4; nt++) {
      const unsigned short* wp = Wt + ((size_t)(col0 + nt * 16 + l15) << 8) + k0;
      bf16x8 bhi = *(const bf16x8*)wp;
      bf16x8 blo = *(const bf16x8*)(wp + 65536);
      acc[nt] = __builtin_amdgcn_mfma_f32_16x16x32_bf16(ahi, bhi, acc[nt], 0, 0, 0);
      acc[nt] = __builtin_amdgcn_mfma_f32_16x16x32_bf16(alo, bhi, acc[nt], 0, 0, 0);
      acc[nt] = __builtin_amdgcn_mfma_f32_16x16x32_bf16(ahi, blo, acc[nt], 0, 0, 0);
    }
  }

  // epilogue. C-layout: row(t_local)=quad*4+reg, col(d)=nt*16+l15.
  const float s1 = 0.424664717f;  // sqrt(log2(e)/8)
  const int b = mbase >> 11;
  const int tb0 = mbase & 2047;
  const size_t bh = (size_t)(b * NH + wave);
  // Kb: 16 scalar stores (4x32B segments per instr, line-combinable)
#pragma unroll
  for (int nt = 0; nt < 4; nt++) {
    int d = nt * 16 + l15;
    int tq = tb0 + quad * 4;
    Kb[(bh * T_SEQ + tq + 0) * DH + d] = f2bf_rne(acc[nt][0] * s1);
    Kb[(bh * T_SEQ + tq + 1) * DH + d] = f2bf_rne(acc[nt][1] * s1);
    Kb[(bh * T_SEQ + tq + 2) * DH + d] = f2bf_rne(acc[nt][2] * s1);
    Kb[(bh * T_SEQ + tq + 3) * DH + d] = f2bf_rne(acc[nt][3] * s1);
    // ldsT[d][t]: t-major ushort4 straight from regs
    ushort4 vp;
    vp.x = f2bf_rne(acc[nt][0]);
    vp.y = f2bf_rne(acc[nt][1]);
    vp.z = f2bf_rne(acc[nt][2]);
    vp.w = f2bf_rne(acc[nt][3]);
    *(ushort4*)&ldsT[wave][d * 16 + quad * 4] = vp;
  }
  __builtin_amdgcn_s_waitcnt(0xC07F);  // lgkmcnt(0); wave-private region
  // Vt: 2 x (linear ds_read_b128 + 16B store); 32B contiguous per d
#pragma unroll
  for (int i = 0; i < 2; i++) {
    int unit = i * 64 + lane;
    int d = unit >> 1;
    int hhalf = unit & 1;
    ushort4 v0 = *(const ushort4*)&ldsT[wave][d * 16 + hhalf * 8];
    ushort4 v1 = *(const ushort4*)&ldsT[wave][d * 16 + hhalf * 8 + 4];
    unsigned short* vb = &Vt[(bh * DH + d) * T_SEQ + tb0 + hhalf * 8];
    *(ushort4*)vb = v0;
    *(ushort4*)(vb + 4) = v1;
  }
}

// ---------------------------------------------------------------------------
// attn: round-3 single-dispatch version (known-good, ~70us; the 2-way split
// cost +21us in round-8). Dbuf K/V + counted vmcnt, setprio, XCD swizzle.
// ---------------------------------------------------------------------------
__global__ __launch_bounds__(256, 4) void attn(
    const unsigned short* __restrict__ Kb, const unsigned short* __restrict__ Vt,
    float* __restrict__ out) {
  __shared__ __align__(16) unsigned short ldsK[2][64 * 64];
  __shared__ __align__(16) unsigned short ldsV[2][64 * 64];
  __shared__ __align__(16) unsigned short ldsP[4][16 * 64];
  const int tid = threadIdx.x;
  const int wave = tid >> 6;
  const int lane = tid & 63;
  const int l15 = lane & 15;
  const int quad = lane >> 4;
  const int lbid = (blockIdx.x & 7) * 128 + (blockIdx.x >> 3);  // XCD swizzle
  const int bh = lbid >> 5;
  const int qtile = lbid & 31;
  const unsigned short* Kbh = Kb + (size_t)bh * T_SEQ * DH;
  const unsigned short* Vbh = Vt + (size_t)bh * DH * T_SEQ;

  const int qrow = qtile * 64 + wave * 16 + l15;
  bf16x8 aq0 = *(const bf16x8*)&Kbh[qrow * DH + quad * 8];
  bf16x8 aq1 = *(const bf16x8*)&Kbh[qrow * DH + 32 + quad * 8];

  f32x4 o[4];
  float lsum[4];
#pragma unroll
  for (int i = 0; i < 4; i++) {
    o[i] = (f32x4){0.f, 0.f, 0.f, 0.f};
    lsum[i] = 0.f;
  }
  unsigned short* Pw = ldsP[wave];

  auto stage = [&](int t, int buf) {
#pragma unroll
    for (int i = 0; i < 2; i++) {
      int slot = i * 256 + tid;
      int r = slot >> 3;
      int c = (slot & 7) ^ (r & 7);
      async_cp16(&Kbh[(t * 64 + r) * DH + c * 8],
                 &ldsK[buf][(i * 256 + wave * 64) * 8]);
      async_cp16(&Vbh[(size_t)r * T_SEQ + t * 64 + c * 8],
                 &ldsV[buf][(i * 256 + wave * 64) * 8]);
    }
  };

  stage(0, 0);

  for (int kt = 0; kt < 32; kt++) {
    const int cur = kt & 1;
    if (kt < 31) {
      stage(kt + 1, cur ^ 1);
      asm volatile("s_waitcnt vmcnt(4)" ::: "memory");
    } else {
      asm volatile("s_waitcnt vmcnt(0)" ::: "memory");
    }
    __builtin_amdgcn_s_barrier();
    __builtin_amdgcn_sched_barrier(0);

    const unsigned short* Kl = ldsK[cur];
    const unsigned short* Vl = ldsV[cur];

    f32x4 sfr[4];
    __builtin_amdgcn_s_setprio(1);
#pragma unroll
    for (int nt = 0; nt < 4; nt++) {
      int key = nt * 16 + l15;
      bf16x8 kf0 = *(const bf16x8*)&Kl[key * 64 + ((quad ^ (key & 7)) << 3)];
      bf16x8 kf1 = *(const bf16x8*)&Kl[key * 64 + (((4 + quad) ^ (key & 7)) << 3)];
      f32x4 s = {0.f, 0.f, 0.f, 0.f};
      s = __builtin_amdgcn_mfma_f32_16x16x32_bf16(aq0, kf0, s, 0, 0, 0);
      s = __builtin_amdgcn_mfma_f32_16x16x32_bf16(aq1, kf1, s, 0, 0, 0);
      sfr[nt] = s;
    }
    __builtin_amdgcn_s_setprio(0);

#pragma unroll
    for (int nt = 0; nt < 4; nt++) {
      int col = nt * 16 + l15;
#pragma unroll
      for (int reg = 0; reg < 4; reg++) {
        float v = sfr[nt][reg];
        float e = __builtin_amdgcn_exp2f(fmaxf(v, 0.2f * v));
        lsum[reg] += e;
        int row = quad * 4 + reg;
        Pw[(row << 6) + (((((col >> 3) ^ (row & 7))) << 3) | (col & 7))] =
            (unsigned short)(__builtin_bit_cast(unsigned int, e) >> 16);
      }
    }
    __builtin_amdgcn_s_waitcnt(0xC07F);  // lgkmcnt(0)

    __builtin_amdgcn_s_setprio(1);
#pragma unroll
    for (int kc = 0; kc < 2; kc++) {
      bf16x8 ap = *(const bf16x8*)&Pw[(l15 << 6) + ((((kc << 2) + quad) ^ (l15 & 7)) << 3)];
#pragma unroll
      for (int nt = 0; nt < 4; nt++) {
        int d = nt * 16 + l15;
        bf16x8 vf = *(const bf16x8*)&Vl[(d << 6) + ((((kc << 2) + quad) ^ (d & 7)) << 3)];
        o[nt] = __builtin_amdgcn_mfma_f32_16x16x32_bf16(ap, vf, o[nt], 0, 0, 0);
      }
    }
    __builtin_amdgcn_s_setprio(0);
    __builtin_amdgcn_sched_barrier(0);
    __builtin_amdgcn_s_barrier();
  }

  float inv[4];
#pragma unroll
  for (int reg = 0; reg < 4; reg++) {
    float l = lsum[reg];
    l += __shfl_xor(l, 1, 64);
    l += __shfl_xor(l, 2, 64);
    l += __shfl_xor(l, 4, 64);
    l += __shfl_xor(l, 8, 64);
    inv[reg] = 1.0f / l;
  }
  const int b = bh >> 2, head = bh & 3;
#pragma unroll
  for (int nt = 0; nt < 4; nt++) {
    int d = nt * 16 + l15;
#pragma unroll
    for (int reg = 0; reg < 4; reg++) {
      int trow = qtile * 64 + wave * 16 + quad * 4 + reg;
      out[((size_t)b * T_SEQ + trow) * 256 + head * 64 + d] = o[nt][reg] * inv[reg];
    }
  }
}

extern "C" void kernel_launch(void* const* d_in, const int* in_sizes, int n_in,
                              void* d_out, int out_size, void* d_ws, size_t ws_size,
                              hipStream_t stream) {
  const float* h = (const float*)d_in[0];
  const float* W = (const float*)d_in[1];
  float* out = (float*)d_out;
  // workspace: Kb 8 MB + Vt 8 MB + Wt 256 KB
  unsigned short* Kb = (unsigned short*)d_ws;
  unsigned short* Vt = Kb + (size_t)32 * T_SEQ * DH;
  unsigned short* Wt = Vt + (size_t)32 * T_SEQ * DH;
  wprep<<<256, 256, 0, stream>>>(W, Wt);
  wh_gemm<<<1024, 256, 0, stream>>>(h, Wt, Kb, Vt);
  attn<<<32 * 32, 256, 0, stream>>>(Kb, Vt, out);
}

// Round 11
// 149.339 us; speedup vs baseline: 1.1052x; 1.0632x over previous
//
#include <hip/hip_runtime.h>

#define T_SEQ 2048
#define NH 4
#define DH 64

typedef __bf16 bf16x8 __attribute__((ext_vector_type(8)));
typedef float f32x4 __attribute__((ext_vector_type(4)));
typedef unsigned short u16x8 __attribute__((ext_vector_type(8)));

__device__ __forceinline__ unsigned short f2bf_rne(float x) {
  unsigned int u = __builtin_bit_cast(unsigned int, x);
  u += 0x7fffu + ((u >> 16) & 1u);
  return (unsigned short)(u >> 16);
}

__device__ __forceinline__ void async_cp16(const unsigned short* g, unsigned short* l) {
  __builtin_amdgcn_global_load_lds(
      (const __attribute__((address_space(1))) unsigned int*)g,
      (__attribute__((address_space(3))) unsigned int*)l, 16, 0, 0);
}

// ---------------------------------------------------------------------------
// wprep: W (256x256 fp32, [k][n]) -> Wt ([n][k] bf16, hi plane + lo plane).
// ---------------------------------------------------------------------------
__global__ __launch_bounds__(256) void wprep(const float* __restrict__ W,
                                             unsigned short* __restrict__ Wt) {
  int tid = blockIdx.x * 256 + threadIdx.x;  // 65536 elems
  int k = tid >> 8, n = tid & 255;
  float w = W[tid];
  unsigned int u = __builtin_bit_cast(unsigned int, w);
  Wt[n * 256 + k] = (unsigned short)(u >> 16);
  float lo = w - __builtin_bit_cast(float, u & 0xffff0000u);
  Wt[65536 + n * 256 + k] =
      (unsigned short)(__builtin_bit_cast(unsigned int, lo) >> 16);
}

// ---------------------------------------------------------------------------
// wh_gemm v3 (revert: v4's 16-row blocks doubled Wt L2 traffic and regressed
// ~10us; v3 measured ~26-30us). 512 blocks x 32 rows, bf16 MFMA hi/lo split.
// ---------------------------------------------------------------------------
__global__ __launch_bounds__(256, 2) void wh_gemm(
    const float* __restrict__ h, const unsigned short* __restrict__ Wt,
    unsigned short* __restrict__ Kb, unsigned short* __restrict__ Vt) {
  __shared__ __align__(16) unsigned short Ahi[32 * 256];  // [row][chunk^row&7]
  __shared__ __align__(16) unsigned short Alo[32 * 256];
  const int tid = threadIdx.x;
  const int wave = tid >> 6;
  const int lane = tid & 63;
  const int l15 = lane & 15;
  const int quad = lane >> 4;
  const int mbase = blockIdx.x * 32;  // 512 blocks
  const int col0 = wave * 64;         // one head per wave

  {
    const int r = tid >> 3;
    const int cbase = (tid & 7) * 4;
    const float4* hp = (const float4*)(h + ((size_t)(mbase + r) << 8) + cbase * 8);
#pragma unroll
    for (int j = 0; j < 4; j++) {
      float4 f0 = hp[2 * j];
      float4 f1 = hp[2 * j + 1];
      u16x8 hi, lo;
#define SPLIT1(v, idx)                                                    \
  {                                                                       \
    unsigned int u_ = __builtin_bit_cast(unsigned int, (v));              \
    hi[idx] = (unsigned short)(u_ >> 16);                                 \
    float r_ = (v) - __builtin_bit_cast(float, u_ & 0xffff0000u);         \
    lo[idx] = (unsigned short)(__builtin_bit_cast(unsigned int, r_) >> 16); \
  }
      SPLIT1(f0.x, 0) SPLIT1(f0.y, 1) SPLIT1(f0.z, 2) SPLIT1(f0.w, 3)
      SPLIT1(f1.x, 4) SPLIT1(f1.y, 5) SPLIT1(f1.z, 6) SPLIT1(f1.w, 7)
#undef SPLIT1
      const int chunk = (cbase + j) ^ (r & 7);
      *(u16x8*)&Ahi[r * 256 + chunk * 8] = hi;
      *(u16x8*)&Alo[r * 256 + chunk * 8] = lo;
    }
  }
  __syncthreads();

  f32x4 acc[2][4];
#pragma unroll
  for (int mt = 0; mt < 2; mt++)
#pragma unroll
    for (int nt = 0; nt < 4; nt++) acc[mt][nt] = (f32x4){0.f, 0.f, 0.f, 0.f};

#pragma unroll 2
  for (int ks = 0; ks < 8; ks++) {
    const int k0 = ks * 32 + quad * 8;
    bf16x8 ahi[2], alo[2];
#pragma unroll
    for (int mt = 0; mt < 2; mt++) {
      const int row = mt * 16 + l15;
      const int ch = (ks * 4 + quad) ^ (row & 7);
      ahi[mt] = *(const bf16x8*)&Ahi[row * 256 + ch * 8];
      alo[mt] = *(const bf16x8*)&Alo[row * 256 + ch * 8];
    }
#pragma unroll
    for (int nt = 0; nt < 4; nt++) {
      const unsigned short* wp = Wt + ((size_t)(col0 + nt * 16 + l15) << 8) + k0;
      bf16x8 bhi = *(const bf16x8*)wp;
      bf16x8 blo = *(const bf16x8*)(wp + 65536);
#pragma unroll
      for (int mt = 0; mt < 2; mt++) {
        acc[mt][nt] = __builtin_amdgcn_mfma_f32_16x16x32_bf16(ahi[mt], bhi, acc[mt][nt], 0, 0, 0);
        acc[mt][nt] = __builtin_amdgcn_mfma_f32_16x16x32_bf16(alo[mt], bhi, acc[mt][nt], 0, 0, 0);
        acc[mt][nt] = __builtin_amdgcn_mfma_f32_16x16x32_bf16(ahi[mt], blo, acc[mt][nt], 0, 0, 0);
      }
    }
  }

  const float s1 = 0.424664717f;  // sqrt(log2(e)/8)
#pragma unroll
  for (int mt = 0; mt < 2; mt++) {
    int row = mbase + mt * 16 + quad * 4;
    int b = row >> 11;
    int tb = row & 2047;
    size_t bh = (size_t)(b * NH + wave);
#pragma unroll
    for (int nt = 0; nt < 4; nt++) {
      int d = nt * 16 + l15;
      Kb[(bh * T_SEQ + tb + 0) * DH + d] = f2bf_rne(acc[mt][nt][0] * s1);
      Kb[(bh * T_SEQ + tb + 1) * DH + d] = f2bf_rne(acc[mt][nt][1] * s1);
      Kb[(bh * T_SEQ + tb + 2) * DH + d] = f2bf_rne(acc[mt][nt][2] * s1);
      Kb[(bh * T_SEQ + tb + 3) * DH + d] = f2bf_rne(acc[mt][nt][3] * s1);
      ushort4 vp;
      vp.x = f2bf_rne(acc[mt][nt][0]);
      vp.y = f2bf_rne(acc[mt][nt][1]);
      vp.z = f2bf_rne(acc[mt][nt][2]);
      vp.w = f2bf_rne(acc[mt][nt][3]);
      *(ushort4*)&Vt[(bh * DH + d) * T_SEQ + tb] = vp;
    }
  }
}

// ---------------------------------------------------------------------------
// attn v3: 32 q-rows per wave (2 m-tiles) -- K/V LDS fragments loaded once,
// used by 2 MFMAs => per-work LDS traffic halves (attn was LDS-BW-bound:
// 16 waves/CU x 20KB x 32 iters over a 128B/cy port ~ 35-40us of the 70).
// Block = 128 q-rows, grid 512 (bijective 8x64 XCD swizzle), LDS 48KB.
// ---------------------------------------------------------------------------
__global__ __launch_bounds__(256, 3) void attn(
    const unsigned short* __restrict__ Kb, const unsigned short* __restrict__ Vt,
    float* __restrict__ out) {
  __shared__ __align__(16) unsigned short ldsK[2][64 * 64];
  __shared__ __align__(16) unsigned short ldsV[2][64 * 64];
  __shared__ __align__(16) unsigned short ldsP[4][32 * 64];
  const int tid = threadIdx.x;
  const int wave = tid >> 6;
  const int lane = tid & 63;
  const int l15 = lane & 15;
  const int quad = lane >> 4;
  const int lbid = (blockIdx.x & 7) * 64 + (blockIdx.x >> 3);  // 512 = 8*64
  const int bh = lbid >> 4;    // 16 blocks per bh
  const int qtile = lbid & 15; // 128 rows each
  const unsigned short* Kbh = Kb + (size_t)bh * T_SEQ * DH;
  const unsigned short* Vbh = Vt + (size_t)bh * DH * T_SEQ;

  // Q A-frags: 2 m-tiles x 2 k-halves
  const int qbase = qtile * 128 + wave * 32;
  bf16x8 aq[2][2];
#pragma unroll
  for (int mt = 0; mt < 2; mt++) {
    const unsigned short* qp = &Kbh[(qbase + mt * 16 + l15) * DH + quad * 8];
    aq[mt][0] = *(const bf16x8*)qp;
    aq[mt][1] = *(const bf16x8*)(qp + 32);
  }

  f32x4 o[2][4];
  float lsum[2][4];
#pragma unroll
  for (int mt = 0; mt < 2; mt++)
#pragma unroll
    for (int i = 0; i < 4; i++) {
      o[mt][i] = (f32x4){0.f, 0.f, 0.f, 0.f};
      lsum[mt][i] = 0.f;
    }
  unsigned short* Pw = ldsP[wave];

  auto stage = [&](int t, int buf) {
#pragma unroll
    for (int i = 0; i < 2; i++) {
      int slot = i * 256 + tid;
      int r = slot >> 3;
      int c = (slot & 7) ^ (r & 7);
      async_cp16(&Kbh[(t * 64 + r) * DH + c * 8],
                 &ldsK[buf][(i * 256 + wave * 64) * 8]);
      async_cp16(&Vbh[(size_t)r * T_SEQ + t * 64 + c * 8],
                 &ldsV[buf][(i * 256 + wave * 64) * 8]);
    }
  };

  stage(0, 0);

  for (int kt = 0; kt < 32; kt++) {
    const int cur = kt & 1;
    if (kt < 31) {
      stage(kt + 1, cur ^ 1);
      asm volatile("s_waitcnt vmcnt(4)" ::: "memory");
    } else {
      asm volatile("s_waitcnt vmcnt(0)" ::: "memory");
    }
    __builtin_amdgcn_s_barrier();
    __builtin_amdgcn_sched_barrier(0);

    const unsigned short* Kl = ldsK[cur];
    const unsigned short* Vl = ldsV[cur];

    // S = Q K^T: K-frag loaded once, feeds both m-tiles
    f32x4 sfr[2][4];
    __builtin_amdgcn_s_setprio(1);
#pragma unroll
    for (int nt = 0; nt < 4; nt++) {
      int key = nt * 16 + l15;
      bf16x8 kf0 = *(const bf16x8*)&Kl[key * 64 + ((quad ^ (key & 7)) << 3)];
      bf16x8 kf1 = *(const bf16x8*)&Kl[key * 64 + (((4 + quad) ^ (key & 7)) << 3)];
#pragma unroll
      for (int mt = 0; mt < 2; mt++) {
        f32x4 s = {0.f, 0.f, 0.f, 0.f};
        s = __builtin_amdgcn_mfma_f32_16x16x32_bf16(aq[mt][0], kf0, s, 0, 0, 0);
        s = __builtin_amdgcn_mfma_f32_16x16x32_bf16(aq[mt][1], kf1, s, 0, 0, 0);
        sfr[mt][nt] = s;
      }
    }
    __builtin_amdgcn_s_setprio(0);

    // softmax numerator + P -> LDS (rows 0-15: mt0, 16-31: mt1)
#pragma unroll
    for (int mt = 0; mt < 2; mt++)
#pragma unroll
      for (int nt = 0; nt < 4; nt++) {
        int col = nt * 16 + l15;
#pragma unroll
        for (int reg = 0; reg < 4; reg++) {
          float v = sfr[mt][nt][reg];
          float e = __builtin_amdgcn_exp2f(fmaxf(v, 0.2f * v));
          lsum[mt][reg] += e;
          int row = mt * 16 + quad * 4 + reg;  // (row&7) == (quad*4+reg)&7
          Pw[(row << 6) + (((((col >> 3) ^ (row & 7))) << 3) | (col & 7))] =
              (unsigned short)(__builtin_bit_cast(unsigned int, e) >> 16);
        }
      }
    __builtin_amdgcn_s_waitcnt(0xC07F);  // lgkmcnt(0)

    // O += P V: V-frag loaded once, feeds both m-tiles
    __builtin_amdgcn_s_setprio(1);
#pragma unroll
    for (int kc = 0; kc < 2; kc++) {
      const int pch = (((kc << 2) + quad) ^ (l15 & 7)) << 3;
      bf16x8 ap0 = *(const bf16x8*)&Pw[(l15 << 6) + pch];
      bf16x8 ap1 = *(const bf16x8*)&Pw[((16 + l15) << 6) + pch];
#pragma unroll
      for (int nt = 0; nt < 4; nt++) {
        int d = nt * 16 + l15;
        bf16x8 vf = *(const bf16x8*)&Vl[(d << 6) + ((((kc << 2) + quad) ^ (d & 7)) << 3)];
        o[0][nt] = __builtin_amdgcn_mfma_f32_16x16x32_bf16(ap0, vf, o[0][nt], 0, 0, 0);
        o[1][nt] = __builtin_amdgcn_mfma_f32_16x16x32_bf16(ap1, vf, o[1][nt], 0, 0, 0);
      }
    }
    __builtin_amdgcn_s_setprio(0);
    __builtin_amdgcn_sched_barrier(0);
    __builtin_amdgcn_s_barrier();
  }

  // epilogue
  const int b = bh >> 2, head = bh & 3;
#pragma unroll
  for (int mt = 0; mt < 2; mt++) {
    float inv[4];
#pragma unroll
    for (int reg = 0; reg < 4; reg++) {
      float l = lsum[mt][reg];
      l += __shfl_xor(l, 1, 64);
      l += __shfl_xor(l, 2, 64);
      l += __shfl_xor(l, 4, 64);
      l += __shfl_xor(l, 8, 64);
      inv[reg] = 1.0f / l;
    }
#pragma unroll
    for (int nt = 0; nt < 4; nt++) {
      int d = nt * 16 + l15;
#pragma unroll
      for (int reg = 0; reg < 4; reg++) {
        int trow = qbase + mt * 16 + quad * 4 + reg;
        out[((size_t)b * T_SEQ + trow) * 256 + head * 64 + d] = o[mt][nt][reg] * inv[reg];
      }
    }
  }
}

extern "C" void kernel_launch(void* const* d_in, const int* in_sizes, int n_in,
                              void* d_out, int out_size, void* d_ws, size_t ws_size,
                              hipStream_t stream) {
  const float* h = (const float*)d_in[0];
  const float* W = (const float*)d_in[1];
  float* out = (float*)d_out;
  // workspace: Kb 8 MB + Vt 8 MB + Wt 256 KB
  unsigned short* Kb = (unsigned short*)d_ws;
  unsigned short* Vt = Kb + (size_t)32 * T_SEQ * DH;
  unsigned short* Wt = Vt + (size_t)32 * T_SEQ * DH;
  wprep<<<256, 256, 0, stream>>>(W, Wt);
  wh_gemm<<<512, 256, 0, stream>>>(h, Wt, Kb, Vt);
  attn<<<512, 256, 0, stream>>>(Kb, Vt, out);
}